// Round 3
// baseline (7585.906 us; speedup 1.0000x reference)
//
#include <hip/hip_runtime.h>
#include <hip/hip_bf16.h>

namespace {
constexpr int BATCH = 256;
constexpr int TENC  = 64;
constexpr int HID   = 1024;
constexpr int VOC   = 128;
constexpr int LDEC  = 32;
constexpr int G4    = 4 * HID;  // 4096
}

// async global->LDS DMA, 16B per lane. LDS dest must be wave-uniform base +
// lane*16 (we pass the per-lane exact pointer; first lane's == base).
__device__ __forceinline__ void async16(const void* g, void* l) {
  __builtin_amdgcn_global_load_lds(
      (const __attribute__((address_space(1))) void*)g,
      (__attribute__((address_space(3))) void*)l, 16, 0, 0);
}

// ---------------------------------------------------------------------------
// init: zero h0, c; tok = delimiter (V-1)
// ---------------------------------------------------------------------------
__global__ __launch_bounds__(256) void k_init(float* __restrict__ h0,
                                              float* __restrict__ c,
                                              int* __restrict__ tok) {
  int i = blockIdx.x * 256 + threadIdx.x;
  h0[i] = 0.f;
  c[i]  = 0.f;
  if (i < BATCH) tok[i] = VOC - 1;
}

// ---------------------------------------------------------------------------
// Precompute P[v][col] = emb[v] @ W[:,col] + b[col]   (V x 4H), enc & dec.
// Tile: 64 rows x 64 cols, BK=32, 256 threads, thread = 4r x 4c.
// grid: (G4/64=64, 128/64=2, 2) = 256 blocks (1/CU).
// A staged manually transposed (padded); B staged via global_load_lds.
// ---------------------------------------------------------------------------
__global__ __launch_bounds__(256) void k_precompute(
    const float* __restrict__ enc_emb, const float* __restrict__ enc_W,
    const float* __restrict__ enc_b,   const float* __restrict__ dec_emb,
    const float* __restrict__ dec_W,   const float* __restrict__ dec_b,
    float* __restrict__ P_enc, float* __restrict__ P_dec) {
  const float* emb; const float* W; const float* bias; float* P;
  if (blockIdx.z == 0) { emb = enc_emb; W = enc_W; bias = enc_b; P = P_enc; }
  else                 { emb = dec_emb; W = dec_W; bias = dec_b; P = P_dec; }

  __shared__ float A_sT[32][68];  // [k][row] transposed, padded
  __shared__ float B_s[32][64];   // [k][col]  (lane-linear for async16)

  const int t    = threadIdx.x;
  const int col0 = blockIdx.x * 64;
  const int v0   = blockIdx.y * 64;
  const int tx   = t & 15;   // 4-col group
  const int ty   = t >> 4;   // 4-row group

  float acc[4][4];
#pragma unroll
  for (int r = 0; r < 4; ++r)
#pragma unroll
    for (int j = 0; j < 4; ++j) acc[r][j] = 0.f;

  for (int k0 = 0; k0 < HID; k0 += 32) {
    __syncthreads();
    // B tile: 32k x 64cols = 512 16B-chunks, 2 per thread, lane-linear.
#pragma unroll
    for (int i = 0; i < 2; ++i) {
      const int idx = t + i * 256;
      const int kk  = idx >> 4;
      const int cq  = (idx & 15) * 4;
      async16(&W[(k0 + kk) * G4 + col0 + cq], &B_s[kk][cq]);
    }
    // A tile: 64 rows x 32k, transposed into padded A_sT (manual).
#pragma unroll
    for (int i = 0; i < 2; ++i) {
      const int idx = t + i * 256;
      const int row = idx >> 3;
      const int kq  = (idx & 7) * 4;
      const float4 val = *(const float4*)&emb[(v0 + row) * HID + k0 + kq];
      A_sT[kq + 0][row] = val.x;
      A_sT[kq + 1][row] = val.y;
      A_sT[kq + 2][row] = val.z;
      A_sT[kq + 3][row] = val.w;
    }
    __syncthreads();
#pragma unroll
    for (int kk = 0; kk < 32; ++kk) {
      const float4 a = *(const float4*)&A_sT[kk][ty * 4];
      const float4 b = *(const float4*)&B_s[kk][tx * 4];
      const float av[4] = {a.x, a.y, a.z, a.w};
      const float bv[4] = {b.x, b.y, b.z, b.w};
#pragma unroll
      for (int r = 0; r < 4; ++r)
#pragma unroll
        for (int j = 0; j < 4; ++j) acc[r][j] += av[r] * bv[j];
    }
  }

  const float4 b4 = *(const float4*)&bias[col0 + tx * 4];
#pragma unroll
  for (int r = 0; r < 4; ++r) {
    float4 o;
    o.x = acc[r][0] + b4.x;
    o.y = acc[r][1] + b4.y;
    o.z = acc[r][2] + b4.z;
    o.w = acc[r][3] + b4.w;
    *(float4*)&P[(v0 + ty * 4 + r) * G4 + col0 + tx * 4] = o;
  }
}

// ---------------------------------------------------------------------------
// One LSTM step, fused GEMM (h_in @ U) + gates + mask.
// Tile: 32 rows x 32 cols x 4 gates, BK=32, 256 threads, thread = 4r x 1c x 4g.
// Double-buffered LDS staged entirely via global_load_lds (lane-linear,
// unpadded; read patterns are 2-addr broadcast (A) / 32-consecutive (B) =>
// conflict-free). One barrier per k-tile; next tile's async loads issue
// BEFORE current tile's compute so the vmcnt(0)-at-barrier drain lands after
// ~1024 cycles of FMA.
// grid: 256 blocks (1/CU); bx%8 pins col-tiles to XCDs (U slice 2MB/XCD L2).
// ---------------------------------------------------------------------------
__global__ __launch_bounds__(256) void k_cell(
    const float* __restrict__ h_in, float* __restrict__ h_out,
    float* __restrict__ c, const float* __restrict__ U,
    const float* __restrict__ P, const int* __restrict__ tok_idx,
    int tok_stride) {
  const int bx = blockIdx.x;
  const int ct = bx & 31;   // column tile (hidden)
  const int rt = bx >> 5;   // row tile (batch)
  const int j0 = ct * 32;
  const int r0 = rt * 32;

  __shared__ float A_s[2][32][32];     // [buf][row][k]
  __shared__ float B_s[2][4][32][32];  // [buf][gate][k][col]

  const int t  = threadIdx.x;
  const int tx = t & 31;   // col within tile
  const int ty = t >> 5;   // row group (8 groups x 4 rows)

  // staging: this thread's 16B chunk (lane-linear in LDS)
  const int sr = t >> 3;        // 0..31
  const int sc = (t & 7) * 4;   // 0..28
  const float* gA = &h_in[(r0 + sr) * HID + sc];
  const float* gB = &U[sr * G4 + j0 + sc];

  // prologue: stage tile 0 into buf 0
  async16(gA, &A_s[0][sr][sc]);
#pragma unroll
  for (int g = 0; g < 4; ++g) async16(gB + g * HID, &B_s[0][g][sr][sc]);

  float acc[4][4];  // [gate][row]
#pragma unroll
  for (int g = 0; g < 4; ++g)
#pragma unroll
    for (int r = 0; r < 4; ++r) acc[g][r] = 0.f;

#pragma unroll 2
  for (int tile = 0; tile < 32; ++tile) {
    const int buf = tile & 1;
    __syncthreads();  // drains stage(buf) issued last iter (vmcnt0 by compiler)
    if (tile < 31) {  // issue next tile's loads, then compute current (overlap)
      const int nb = buf ^ 1;
      const float* gAn = gA + (tile + 1) * 32;
      const float* gBn = gB + (size_t)(tile + 1) * 32 * G4;
      async16(gAn, &A_s[nb][sr][sc]);
#pragma unroll
      for (int g = 0; g < 4; ++g)
        async16(gBn + g * HID, &B_s[nb][g][sr][sc]);
    }
#pragma unroll
    for (int k4 = 0; k4 < 32; k4 += 4) {
      float4 av[4];
#pragma unroll
      for (int r = 0; r < 4; ++r)
        av[r] = *(const float4*)&A_s[buf][ty * 4 + r][k4];
#pragma unroll
      for (int q = 0; q < 4; ++q) {
        const float b0 = B_s[buf][0][k4 + q][tx];
        const float b1 = B_s[buf][1][k4 + q][tx];
        const float b2 = B_s[buf][2][k4 + q][tx];
        const float b3 = B_s[buf][3][k4 + q][tx];
#pragma unroll
        for (int r = 0; r < 4; ++r) {
          const float a = ((const float*)&av[r])[q];
          acc[0][r] += a * b0;
          acc[1][r] += a * b1;
          acc[2][r] += a * b2;
          acc[3][r] += a * b3;
        }
      }
    }
  }

  const int col = j0 + tx;
#pragma unroll
  for (int r = 0; r < 4; ++r) {
    const int row   = r0 + ty * 4 + r;
    const int token = tok_idx[row * tok_stride];
    const float* Px = P + token * G4;
    const float zi = acc[0][r] + Px[col];
    const float zf = acc[1][r] + Px[HID + col];
    const float zg = acc[2][r] + Px[2 * HID + col];
    const float zo = acc[3][r] + Px[3 * HID + col];
    const float ig = 1.f / (1.f + expf(-zi));
    const float fg = 1.f / (1.f + expf(-zf));
    const float gg = tanhf(zg);
    const float og = 1.f / (1.f + expf(-zo));
    const float c_old = c[row * HID + col];
    const float c2 = fg * c_old + ig * gg;
    const float h2 = og * tanhf(c2);
    if (token != 0) {
      h_out[row * HID + col] = h2;
      c[row * HID + col]     = c2;
    } else {
      h_out[row * HID + col] = h_in[row * HID + col];
      // c unchanged
    }
  }
}

// ---------------------------------------------------------------------------
// Decoder output: logits = h @ out_W + out_b; softmax -> y; argmax -> tok.
// grid: BATCH/2 blocks x 128 threads (thread = one vocab col, 2 batch rows).
// ---------------------------------------------------------------------------
__global__ __launch_bounds__(128) void k_logits(
    const float* __restrict__ h, const float* __restrict__ out_W,
    const float* __restrict__ out_b, float* __restrict__ out, int t,
    int* __restrict__ tok) {
  const int b0 = blockIdx.x * 2;
  const int v  = threadIdx.x;

  __shared__ float h_s[2][HID];
  __shared__ float red_v[128];
  __shared__ int   red_i[128];

#pragma unroll
  for (int i = 0; i < 4; ++i) {
    int q  = v + i * 128;
    int r  = q >> 8;
    int kq = (q & 255) * 4;
    *(float4*)&h_s[r][kq] = *(const float4*)&h[(b0 + r) * HID + kq];
  }
  __syncthreads();

  float acc[2];
  acc[0] = out_b[v];
  acc[1] = acc[0];
#pragma unroll 8
  for (int k = 0; k < HID; ++k) {
    const float w = out_W[k * VOC + v];
    acc[0] += h_s[0][k] * w;
    acc[1] += h_s[1][k] * w;
  }

  for (int r = 0; r < 2; ++r) {
    const int b = b0 + r;
    red_v[v] = acc[r];
    red_i[v] = v;
    __syncthreads();
    for (int s = 64; s > 0; s >>= 1) {
      if (v < s) {
        const float ov = red_v[v + s];
        const int   oi = red_i[v + s];
        if (ov > red_v[v] || (ov == red_v[v] && oi < red_i[v])) {
          red_v[v] = ov;
          red_i[v] = oi;
        }
      }
      __syncthreads();
    }
    const float mx  = red_v[0];
    const int amax  = red_i[0];
    __syncthreads();
    const float e = expf(acc[r] - mx);
    red_v[v] = e;
    __syncthreads();
    for (int s = 64; s > 0; s >>= 1) {
      if (v < s) red_v[v] += red_v[v + s];
      __syncthreads();
    }
    const float sum = red_v[0];
    out[b * (LDEC * VOC) + t * VOC + v] = e / sum;
    if (v == 0) {
      tok[b] = amax;
      out[BATCH * LDEC * VOC + t * BATCH + b] = (float)amax;
    }
    __syncthreads();
  }
}

// ---------------------------------------------------------------------------
extern "C" void kernel_launch(void* const* d_in, const int* in_sizes, int n_in,
                              void* d_out, int out_size, void* d_ws,
                              size_t ws_size, hipStream_t stream) {
  (void)in_sizes; (void)n_in; (void)out_size; (void)ws_size;
  const int*   inputs  = (const int*)d_in[0];
  const float* enc_emb = (const float*)d_in[2];
  const float* enc_W   = (const float*)d_in[3];
  const float* enc_U   = (const float*)d_in[4];
  const float* enc_b   = (const float*)d_in[5];
  const float* dec_emb = (const float*)d_in[6];
  const float* dec_W   = (const float*)d_in[7];
  const float* dec_U   = (const float*)d_in[8];
  const float* dec_b   = (const float*)d_in[9];
  const float* out_W   = (const float*)d_in[10];
  const float* out_b   = (const float*)d_in[11];
  float* out = (float*)d_out;

  float* ws    = (float*)d_ws;
  float* P_enc = ws;                       // V*4H
  float* P_dec = P_enc + VOC * G4;         // V*4H
  float* h0    = P_dec + VOC * G4;         // B*H
  float* h1    = h0 + BATCH * HID;         // B*H
  float* c     = h1 + BATCH * HID;         // B*H
  int*   tok   = (int*)(c + BATCH * HID);  // B

  k_init<<<(BATCH * HID) / 256, 256, 0, stream>>>(h0, c, tok);

  dim3 pgrid(G4 / 64, 2, 2);
  k_precompute<<<pgrid, 256, 0, stream>>>(enc_emb, enc_W, enc_b, dec_emb,
                                          dec_W, dec_b, P_enc, P_dec);

  float* hin  = h0;
  float* hout = h1;
  for (int t = 0; t < TENC; ++t) {
    k_cell<<<256, 256, 0, stream>>>(hin, hout, c, enc_U, P_enc, inputs + t,
                                    TENC);
    float* tmp = hin; hin = hout; hout = tmp;
  }
  for (int s = 0; s < LDEC; ++s) {
    k_cell<<<256, 256, 0, stream>>>(hin, hout, c, dec_U, P_dec, tok, 1);
    k_logits<<<BATCH / 2, 128, 0, stream>>>(hout, out_W, out_b, out, s, tok);
    float* tmp = hin; hin = hout; hout = tmp;
  }
}

// Round 5
// 6332.744 us; speedup vs baseline: 1.1979x; 1.1979x over previous
//
#include <hip/hip_runtime.h>
#include <hip/hip_bf16.h>

namespace {
constexpr int BATCH = 256;
constexpr int TENC  = 64;
constexpr int HID   = 1024;
constexpr int VOC   = 128;
constexpr int LDEC  = 32;
constexpr int G4    = 4 * HID;  // 4096
}

// async global->LDS DMA, 16B per lane. LDS dest must be wave-uniform base +
// lane*16; all our staging layouts are lane-linear (LDS byte off = chunk*16).
__device__ __forceinline__ void async16(const void* g, void* l) {
  __builtin_amdgcn_global_load_lds(
      (const __attribute__((address_space(1))) void*)g,
      (__attribute__((address_space(3))) void*)l, 16, 0, 0);
}

// ---------------------------------------------------------------------------
// init: zero h0, c; tok = delimiter (V-1)
// ---------------------------------------------------------------------------
__global__ __launch_bounds__(256) void k_init(float* __restrict__ h0,
                                              float* __restrict__ c,
                                              int* __restrict__ tok) {
  int i = blockIdx.x * 256 + threadIdx.x;
  h0[i] = 0.f;
  c[i]  = 0.f;
  if (i < BATCH) tok[i] = VOC - 1;
}

// ---------------------------------------------------------------------------
// Precompute P[v][col] = emb[v] @ W[:,col] + b[col]   (V x 4H), enc & dec.
// Block: 64 v-rows x 64 cols, BK=32, 256 threads, thread = 4r x 4c (16 acc).
// Double-buffered, all staging via global_load_lds, all reads b128.
// grid: (G4/64=64, 128/64=2, 2) = 256 blocks.
// ---------------------------------------------------------------------------
__global__ __launch_bounds__(256) void k_precompute(
    const float* __restrict__ enc_emb, const float* __restrict__ enc_W,
    const float* __restrict__ enc_b,   const float* __restrict__ dec_emb,
    const float* __restrict__ dec_W,   const float* __restrict__ dec_b,
    float* __restrict__ P_enc, float* __restrict__ P_dec) {
  const float* emb; const float* W; const float* bias; float* P;
  if (blockIdx.z == 0) { emb = enc_emb; W = enc_W; bias = enc_b; P = P_enc; }
  else                 { emb = dec_emb; W = dec_W; bias = dec_b; P = P_dec; }

  __shared__ float A_s[2][64][32];  // [buf][row][k]   8 KB x2
  __shared__ float B_s[2][32][64];  // [buf][k][col]   8 KB x2

  const int t    = threadIdx.x;
  const int col0 = blockIdx.x * 64;
  const int v0   = blockIdx.y * 64;
  const int tx   = t & 15;   // col group (4 cols)
  const int ty   = t >> 4;   // row group (4 rows)

  const int a_row = t >> 3, a_kq = (t & 7) * 4;
  const int b_k   = t >> 4, b_cq = (t & 15) * 4;

  float acc[4][4];
#pragma unroll
  for (int r = 0; r < 4; ++r)
#pragma unroll
    for (int j = 0; j < 4; ++j) acc[r][j] = 0.f;

  // prologue: stage tile 0 -> buf 0
  async16(&emb[(v0 + a_row) * HID + a_kq], &A_s[0][a_row][a_kq]);
  async16(&emb[(v0 + 32 + a_row) * HID + a_kq], &A_s[0][32 + a_row][a_kq]);
  async16(&W[b_k * G4 + col0 + b_cq], &B_s[0][b_k][b_cq]);
  async16(&W[(16 + b_k) * G4 + col0 + b_cq], &B_s[0][16 + b_k][b_cq]);

  for (int tile = 0; tile < 32; ++tile) {
    const int buf = tile & 1;
    __syncthreads();  // drains the async16s for this buf
    if (tile < 31) {
      const int nb = buf ^ 1;
      const int k0 = (tile + 1) * 32;
      async16(&emb[(v0 + a_row) * HID + k0 + a_kq], &A_s[nb][a_row][a_kq]);
      async16(&emb[(v0 + 32 + a_row) * HID + k0 + a_kq],
              &A_s[nb][32 + a_row][a_kq]);
      async16(&W[(k0 + b_k) * G4 + col0 + b_cq], &B_s[nb][b_k][b_cq]);
      async16(&W[(k0 + 16 + b_k) * G4 + col0 + b_cq],
              &B_s[nb][16 + b_k][b_cq]);
    }
#pragma unroll
    for (int k4 = 0; k4 < 32; k4 += 4) {
      float4 av[4];
#pragma unroll
      for (int r = 0; r < 4; ++r)
        av[r] = *(const float4*)&A_s[buf][ty * 4 + r][k4];
#pragma unroll
      for (int q = 0; q < 4; ++q) {
        const float4 b = *(const float4*)&B_s[buf][k4 + q][tx * 4];
#pragma unroll
        for (int r = 0; r < 4; ++r) {
          const float a = ((const float*)&av[r])[q];
          acc[r][0] += a * b.x;
          acc[r][1] += a * b.y;
          acc[r][2] += a * b.z;
          acc[r][3] += a * b.w;
        }
      }
    }
  }

  const float4 b4 = *(const float4*)&bias[col0 + tx * 4];
#pragma unroll
  for (int r = 0; r < 4; ++r) {
    float4 o;
    o.x = acc[r][0] + b4.x;
    o.y = acc[r][1] + b4.y;
    o.z = acc[r][2] + b4.z;
    o.w = acc[r][3] + b4.w;
    *(float4*)&P[(v0 + ty * 4 + r) * G4 + col0 + tx * 4] = o;
  }
}

// ---------------------------------------------------------------------------
// One LSTM step, fused GEMM (h_in @ U) + gates + mask.
// Block: 32 batch rows x 32 hidcols x 4 gates = 32 x 128 N-cols; BK=32;
// 256 threads = 8 rowg x 32 colg; thread = 4 rows x 4 N-cols (16 acc).
// B LDS layout [k][g*32+j] folds gates into N -> all reads b128:
//   per 4k chunk/wave: 4 b128 A (2-way bcast, free) + 4 b128 B (512B stream)
//   + 64 FMA  => FMA-bound (~33K cyc/CU/step vs ~24K LDS).
// Gates re-united via z_s LDS exchange before the epilogue.
// grid: 8 row-tiles x 32 col-tiles = 256 blocks (1/CU).
// ---------------------------------------------------------------------------
__global__ __launch_bounds__(256) void k_cell(
    const float* __restrict__ h_in, float* __restrict__ h_out,
    float* __restrict__ c, const float* __restrict__ U,
    const float* __restrict__ P, const int* __restrict__ tok_idx,
    int tok_stride) {
  const int bx = blockIdx.x;
  const int ct = bx & 31;   // hidcol tile
  const int rt = bx >> 5;   // row tile
  const int j0 = ct * 32;
  const int r0 = rt * 32;

  __shared__ float A_s[2][32][32];   //  8 KB
  __shared__ float B_s[2][32][128];  // 32 KB
  __shared__ float z_s[32][128];     // 16 KB   (total 56 KB)

  const int t    = threadIdx.x;
  const int colg = t & 31;  // N-col group (4 cols)
  const int rowg = t >> 5;  // row group (4 rows)

  const int a_row = t >> 3, a_kq = (t & 7) * 4;
  const float* gA = &h_in[(r0 + a_row) * HID + a_kq];
  const float* gBp[4];
  int   b_k[4], b_ncq[4];
#pragma unroll
  for (int i = 0; i < 4; ++i) {
    const int cc = t + i * 256;
    b_k[i]   = cc >> 5;
    b_ncq[i] = (cc & 31) * 4;
    gBp[i] = &U[b_k[i] * G4 + (b_ncq[i] >> 5) * HID + j0 + (b_ncq[i] & 31)];
  }

  // prologue: stage tile 0 -> buf 0
  async16(gA, &A_s[0][a_row][a_kq]);
#pragma unroll
  for (int i = 0; i < 4; ++i)
    async16(gBp[i], &B_s[0][b_k[i]][b_ncq[i]]);

  float acc[4][4];  // [row][ncol]
#pragma unroll
  for (int r = 0; r < 4; ++r)
#pragma unroll
    for (int j = 0; j < 4; ++j) acc[r][j] = 0.f;

  for (int tile = 0; tile < 32; ++tile) {
    const int buf = tile & 1;
    __syncthreads();  // drains stage(buf) issued last iter
    if (tile < 31) {
      const int nb = buf ^ 1;
      const float* gAn = gA + (tile + 1) * 32;
      const size_t bo  = (size_t)(tile + 1) * 32 * G4;
      async16(gAn, &A_s[nb][a_row][a_kq]);
#pragma unroll
      for (int i = 0; i < 4; ++i)
        async16(gBp[i] + bo, &B_s[nb][b_k[i]][b_ncq[i]]);
    }
#pragma unroll
    for (int k4 = 0; k4 < 32; k4 += 4) {
      float4 av[4];
#pragma unroll
      for (int r = 0; r < 4; ++r)
        av[r] = *(const float4*)&A_s[buf][rowg * 4 + r][k4];
#pragma unroll
      for (int q = 0; q < 4; ++q) {
        const float4 b = *(const float4*)&B_s[buf][k4 + q][colg * 4];
#pragma unroll
        for (int r = 0; r < 4; ++r) {
          const float a = ((const float*)&av[r])[q];
          acc[r][0] += a * b.x;
          acc[r][1] += a * b.y;
          acc[r][2] += a * b.z;
          acc[r][3] += a * b.w;
        }
      }
    }
  }

  // gate exchange: z_s[row][g*32+j]
#pragma unroll
  for (int r = 0; r < 4; ++r) {
    float4 o;
    o.x = acc[r][0]; o.y = acc[r][1]; o.z = acc[r][2]; o.w = acc[r][3];
    *(float4*)&z_s[rowg * 4 + r][colg * 4] = o;
  }
  __syncthreads();

  // epilogue: thread -> 4 (row, hidcol) pairs: row=(t>>5)*4+p, hc=t&31
  const int hc = t & 31;
#pragma unroll
  for (int p = 0; p < 4; ++p) {
    const int row  = (t >> 5) * 4 + p;
    const int grow = r0 + row;
    const int token = tok_idx[grow * tok_stride];
    const float* Px = P + (size_t)token * G4;
    const int col = j0 + hc;
    const float zi = z_s[row][hc]       + Px[col];
    const float zf = z_s[row][32 + hc]  + Px[HID + col];
    const float zg = z_s[row][64 + hc]  + Px[2 * HID + col];
    const float zo = z_s[row][96 + hc]  + Px[3 * HID + col];
    const float ig = 1.f / (1.f + expf(-zi));
    const float fg = 1.f / (1.f + expf(-zf));
    const float gg = tanhf(zg);
    const float og = 1.f / (1.f + expf(-zo));
    const float c_old = c[grow * HID + col];
    const float c2 = fg * c_old + ig * gg;
    const float h2 = og * tanhf(c2);
    if (token != 0) {
      h_out[grow * HID + col] = h2;
      c[grow * HID + col]     = c2;
    } else {
      h_out[grow * HID + col] = h_in[grow * HID + col];
      // c unchanged
    }
  }
}

// ---------------------------------------------------------------------------
// Decoder output: logits = h @ out_W + out_b; softmax -> y; argmax -> tok.
// grid: BATCH/2 blocks x 128 threads (thread = one vocab col, 2 batch rows).
// ---------------------------------------------------------------------------
__global__ __launch_bounds__(128) void k_logits(
    const float* __restrict__ h, const float* __restrict__ out_W,
    const float* __restrict__ out_b, float* __restrict__ out, int t,
    int* __restrict__ tok) {
  const int b0 = blockIdx.x * 2;
  const int v  = threadIdx.x;

  __shared__ float h_s[2][HID];
  __shared__ float red_v[128];
  __shared__ int   red_i[128];

#pragma unroll
  for (int i = 0; i < 4; ++i) {
    int q  = v + i * 128;
    int r  = q >> 8;
    int kq = (q & 255) * 4;
    *(float4*)&h_s[r][kq] = *(const float4*)&h[(b0 + r) * HID + kq];
  }
  __syncthreads();

  float acc[2];
  acc[0] = out_b[v];
  acc[1] = acc[0];
#pragma unroll 8
  for (int k = 0; k < HID; ++k) {
    const float w = out_W[k * VOC + v];
    acc[0] += h_s[0][k] * w;
    acc[1] += h_s[1][k] * w;
  }

  for (int r = 0; r < 2; ++r) {
    const int b = b0 + r;
    red_v[v] = acc[r];
    red_i[v] = v;
    __syncthreads();
    for (int s = 64; s > 0; s >>= 1) {
      if (v < s) {
        const float ov = red_v[v + s];
        const int   oi = red_i[v + s];
        if (ov > red_v[v] || (ov == red_v[v] && oi < red_i[v])) {
          red_v[v] = ov;
          red_i[v] = oi;
        }
      }
      __syncthreads();
    }
    const float mx  = red_v[0];
    const int amax  = red_i[0];
    __syncthreads();
    const float e = expf(acc[r] - mx);
    red_v[v] = e;
    __syncthreads();
    for (int s = 64; s > 0; s >>= 1) {
      if (v < s) red_v[v] += red_v[v + s];
      __syncthreads();
    }
    const float sum = red_v[0];
    out[b * (LDEC * VOC) + t * VOC + v] = e / sum;
    if (v == 0) {
      tok[b] = amax;
      out[BATCH * LDEC * VOC + t * BATCH + b] = (float)amax;
    }
    __syncthreads();
  }
}

// ---------------------------------------------------------------------------
extern "C" void kernel_launch(void* const* d_in, const int* in_sizes, int n_in,
                              void* d_out, int out_size, void* d_ws,
                              size_t ws_size, hipStream_t stream) {
  (void)in_sizes; (void)n_in; (void)out_size; (void)ws_size;
  const int*   inputs  = (const int*)d_in[0];
  const float* enc_emb = (const float*)d_in[2];
  const float* enc_W   = (const float*)d_in[3];
  const float* enc_U   = (const float*)d_in[4];
  const float* enc_b   = (const float*)d_in[5];
  const float* dec_emb = (const float*)d_in[6];
  const float* dec_W   = (const float*)d_in[7];
  const float* dec_U   = (const float*)d_in[8];
  const float* dec_b   = (const float*)d_in[9];
  const float* out_W   = (const float*)d_in[10];
  const float* out_b   = (const float*)d_in[11];
  float* out = (float*)d_out;

  float* ws    = (float*)d_ws;
  float* P_enc = ws;                       // V*4H
  float* P_dec = P_enc + VOC * G4;         // V*4H
  float* h0    = P_dec + VOC * G4;         // B*H
  float* h1    = h0 + BATCH * HID;         // B*H
  float* c     = h1 + BATCH * HID;         // B*H
  int*   tok   = (int*)(c + BATCH * HID);  // B

  k_init<<<(BATCH * HID) / 256, 256, 0, stream>>>(h0, c, tok);

  dim3 pgrid(G4 / 64, 2, 2);
  k_precompute<<<pgrid, 256, 0, stream>>>(enc_emb, enc_W, enc_b, dec_emb,
                                          dec_W, dec_b, P_enc, P_dec);

  float* hin  = h0;
  float* hout = h1;
  for (int t = 0; t < TENC; ++t) {
    k_cell<<<256, 256, 0, stream>>>(hin, hout, c, enc_U, P_enc, inputs + t,
                                    TENC);
    float* tmp = hin; hin = hout; hout = tmp;
  }
  for (int s = 0; s < LDEC; ++s) {
    k_cell<<<256, 256, 0, stream>>>(hin, hout, c, dec_U, P_dec, tok, 1);
    k_logits<<<BATCH / 2, 128, 0, stream>>>(hout, out_W, out_b, out, s, tok);
    float* tmp = hin; hin = hout; hout = tmp;
  }
}

// Round 7
// 3690.244 us; speedup vs baseline: 2.0557x; 1.7161x over previous
//
#include <hip/hip_runtime.h>
#include <hip/hip_bf16.h>

namespace {
constexpr int BATCH = 256;
constexpr int TENC  = 64;
constexpr int HID   = 1024;
constexpr int VOC   = 128;
constexpr int LDEC  = 32;
constexpr int G4    = 4 * HID;  // 4096
}

using short8 = __attribute__((ext_vector_type(8))) short;   // 8 bf16 (4 VGPR)
using f32x4  = __attribute__((ext_vector_type(4))) float;   // MFMA acc

// async global->LDS DMA, 16B per lane (dest = wave-uniform base + lane*16).
__device__ __forceinline__ void async16(const void* g, void* l) {
  __builtin_amdgcn_global_load_lds(
      (const __attribute__((address_space(1))) void*)g,
      (__attribute__((address_space(3))) void*)l, 16, 0, 0);
}

// bf16 round-to-nearest-even split helpers
__device__ __forceinline__ unsigned short f2bf(float x) {
  unsigned int u = __float_as_uint(x);
  return (unsigned short)((u + 0x7fffu + ((u >> 16) & 1u)) >> 16);
}
__device__ __forceinline__ float bf2f(unsigned short h) {
  return __uint_as_float(((unsigned int)h) << 16);
}

// ---------------------------------------------------------------------------
// init: zero h0, c, hpk0; tok = delimiter
// ---------------------------------------------------------------------------
__global__ __launch_bounds__(256) void k_init(float* __restrict__ h0,
                                              float* __restrict__ c,
                                              unsigned int* __restrict__ hpk0,
                                              int* __restrict__ tok) {
  int i = blockIdx.x * 256 + threadIdx.x;  // 0 .. 256*1024-1
  h0[i] = 0.f;
  c[i]  = 0.f;
  hpk0[i] = 0u;  // 2 splits * 256K ushort = 256K dwords
  if (i < BATCH) tok[i] = VOC - 1;
}

// ---------------------------------------------------------------------------
// Split U (fp32 HIDxG4) into bf16 hi/lo, packed in MFMA B-fragment order:
// chunk16B[( (ct*32 + ks)*8 + f )*64 + kq*16 + coln], elem = kk
//   ct=hidcol>>5, f=gate*2+(j>>4), coln=j&15 (j=hidcol&31), ks=k>>5,
//   kq=(k>>3)&3, kk=k&7.
// grid: (4194304/256, 2)  [y: enc/dec]
// ---------------------------------------------------------------------------
__global__ __launch_bounds__(256) void k_split_u(
    const float* __restrict__ enc_U, const float* __restrict__ dec_U,
    unsigned short* __restrict__ enc_hi, unsigned short* __restrict__ enc_lo,
    unsigned short* __restrict__ dec_hi, unsigned short* __restrict__ dec_lo) {
  const float* U;
  unsigned short *hi_p, *lo_p;
  if (blockIdx.y == 0) { U = enc_U; hi_p = enc_hi; lo_p = enc_lo; }
  else                 { U = dec_U; hi_p = dec_hi; lo_p = dec_lo; }
  const int gid = blockIdx.x * 256 + threadIdx.x;  // 0 .. HID*G4-1
  const int k = gid >> 12;
  const int n = gid & 4095;
  const float x = U[gid];
  const unsigned short h = f2bf(x);
  const unsigned short l = f2bf(x - bf2f(h));
  const int hidcol = n & 1023, gate = n >> 10;
  const int ct = hidcol >> 5, j = hidcol & 31;
  const int f = gate * 2 + (j >> 4), coln = j & 15;
  const int ks = k >> 5, kq = (k >> 3) & 3, kk = k & 7;
  const int addr = ((((ct * 32 + ks) * 8 + f) * 64 + kq * 16 + coln) << 3) + kk;
  hi_p[addr] = h;
  lo_p[addr] = l;
}

// ---------------------------------------------------------------------------
// Precompute P[v][col] = emb[v] @ W[:,col] + b[col]  (fp32, unchanged r5).
// ---------------------------------------------------------------------------
__global__ __launch_bounds__(256) void k_precompute(
    const float* __restrict__ enc_emb, const float* __restrict__ enc_W,
    const float* __restrict__ enc_b,   const float* __restrict__ dec_emb,
    const float* __restrict__ dec_W,   const float* __restrict__ dec_b,
    float* __restrict__ P_enc, float* __restrict__ P_dec) {
  const float* emb; const float* W; const float* bias; float* P;
  if (blockIdx.z == 0) { emb = enc_emb; W = enc_W; bias = enc_b; P = P_enc; }
  else                 { emb = dec_emb; W = dec_W; bias = dec_b; P = P_dec; }

  __shared__ float A_s[2][64][32];
  __shared__ float B_s[2][32][64];

  const int t    = threadIdx.x;
  const int col0 = blockIdx.x * 64;
  const int v0   = blockIdx.y * 64;
  const int tx   = t & 15;
  const int ty   = t >> 4;
  const int a_row = t >> 3, a_kq = (t & 7) * 4;
  const int b_k   = t >> 4, b_cq = (t & 15) * 4;

  float acc[4][4];
#pragma unroll
  for (int r = 0; r < 4; ++r)
#pragma unroll
    for (int j = 0; j < 4; ++j) acc[r][j] = 0.f;

  async16(&emb[(v0 + a_row) * HID + a_kq], &A_s[0][a_row][a_kq]);
  async16(&emb[(v0 + 32 + a_row) * HID + a_kq], &A_s[0][32 + a_row][a_kq]);
  async16(&W[b_k * G4 + col0 + b_cq], &B_s[0][b_k][b_cq]);
  async16(&W[(16 + b_k) * G4 + col0 + b_cq], &B_s[0][16 + b_k][b_cq]);

  for (int tile = 0; tile < 32; ++tile) {
    const int buf = tile & 1;
    __syncthreads();
    if (tile < 31) {
      const int nb = buf ^ 1;
      const int k0 = (tile + 1) * 32;
      async16(&emb[(v0 + a_row) * HID + k0 + a_kq], &A_s[nb][a_row][a_kq]);
      async16(&emb[(v0 + 32 + a_row) * HID + k0 + a_kq],
              &A_s[nb][32 + a_row][a_kq]);
      async16(&W[(k0 + b_k) * G4 + col0 + b_cq], &B_s[nb][b_k][b_cq]);
      async16(&W[(k0 + 16 + b_k) * G4 + col0 + b_cq],
              &B_s[nb][16 + b_k][b_cq]);
    }
#pragma unroll
    for (int k4 = 0; k4 < 32; k4 += 4) {
      float4 av[4];
#pragma unroll
      for (int r = 0; r < 4; ++r)
        av[r] = *(const float4*)&A_s[buf][ty * 4 + r][k4];
#pragma unroll
      for (int q = 0; q < 4; ++q) {
        const float4 b = *(const float4*)&B_s[buf][k4 + q][tx * 4];
#pragma unroll
        for (int r = 0; r < 4; ++r) {
          const float a = ((const float*)&av[r])[q];
          acc[r][0] += a * b.x;
          acc[r][1] += a * b.y;
          acc[r][2] += a * b.z;
          acc[r][3] += a * b.w;
        }
      }
    }
  }

  const float4 b4 = *(const float4*)&bias[col0 + tx * 4];
#pragma unroll
  for (int r = 0; r < 4; ++r) {
    float4 o;
    o.x = acc[r][0] + b4.x;
    o.y = acc[r][1] + b4.y;
    o.z = acc[r][2] + b4.z;
    o.w = acc[r][3] + b4.w;
    *(float4*)&P[(v0 + ty * 4 + r) * G4 + col0 + tx * 4] = o;
  }
}

// ---------------------------------------------------------------------------
// LSTM step via MFMA (bf16 hi/lo x4 products, fp32 acc).
// Block: 32 rows x (32 hidcols x 4 gates = 128 N). 4 waves; wave = gate.
// Wave tile: 32 rows x 32 N = 2x2 fragments of 16x16x32.
// B staged to LDS per BK=64 tile (async16, fragment-packed, lane-linear);
// A (h splits) loaded b128 directly from fragment-packed global.
// grid: 8 rt x 32 ct = 256 blocks (bx&31=ct -> ct%8 pins XCD L2 slices).
// ---------------------------------------------------------------------------
__global__ __launch_bounds__(256) void k_cell(
    const float* __restrict__ h_in, float* __restrict__ h_out,
    float* __restrict__ c,
    const unsigned short* __restrict__ Upk_hi,
    const unsigned short* __restrict__ Upk_lo,
    const unsigned short* __restrict__ hpk_in,
    unsigned short* __restrict__ hpk_out,
    const float* __restrict__ P, const int* __restrict__ tok_idx,
    int tok_stride) {
  const int bx = blockIdx.x;
  const int ct = bx & 31;
  const int rt = bx >> 5;
  const int j0 = ct * 32;
  const int r0 = rt * 32;
  const int t    = threadIdx.x;
  const int lane = t & 63;
  const int g    = t >> 6;  // wave id = gate

  __shared__ char smem[64 * 1024 + 32 * 132 * 4];
  char* Bs = smem;  // [buf][s][ks2][f][lane][16B] : buf*32KB + cc*16B
  float(*z_s)[132] = (float(*)[132])(smem + 64 * 1024);

  const unsigned short* Upk[2] = {Upk_hi, Upk_lo};

  // stage tile T (ksteps 2T,2T+1) into buf: 2048 chunks, 8 per thread
#define STAGE(T, buf)                                                        \
  {                                                                          \
    _Pragma("unroll") for (int i = 0; i < 8; ++i) {                          \
      const int cc = t + i * 256;                                            \
      const int lc = cc & 63, ff = (cc >> 6) & 7, k2 = (cc >> 9) & 1,        \
                ss = cc >> 10;                                               \
      const unsigned short* src =                                            \
          Upk[ss] + ((((ct * 32 + (2 * (T) + k2)) * 8 + ff) * 64 + lc) << 3);\
      async16(src, Bs + (buf) * 32768 + cc * 16);                            \
    }                                                                        \
  }

  f32x4 acc[2][2];
#pragma unroll
  for (int m = 0; m < 2; ++m)
#pragma unroll
    for (int n = 0; n < 2; ++n) acc[m][n] = (f32x4){0.f, 0.f, 0.f, 0.f};

  STAGE(0, 0);

  for (int T = 0; T < 16; ++T) {
    const int buf = T & 1;
    __syncthreads();  // drains this buf's async16 (issued last iter)
    if (T < 15) STAGE(T + 1, buf ^ 1);
#pragma unroll
    for (int ks2 = 0; ks2 < 2; ++ks2) {
      const int ks = 2 * T + ks2;
      short8 a[2][2], b[2][2];
#pragma unroll
      for (int m = 0; m < 2; ++m)
#pragma unroll
        for (int s = 0; s < 2; ++s)
          a[m][s] = *(const short8*)(hpk_in +
              ((((s * 32 + ks) * 16 + (rt * 2 + m)) * 64 + lane) << 3));
#pragma unroll
      for (int nf = 0; nf < 2; ++nf)
#pragma unroll
        for (int s = 0; s < 2; ++s)
          b[nf][s] = *(const short8*)(Bs + buf * 32768 +
              ((s * 1024 + ks2 * 512 + (g * 2 + nf) * 64 + lane) << 4));
#pragma unroll
      for (int m = 0; m < 2; ++m)
#pragma unroll
        for (int n = 0; n < 2; ++n) {
          acc[m][n] = __builtin_amdgcn_mfma_f32_16x16x32_bf16(
              a[m][0], b[n][0], acc[m][n], 0, 0, 0);
          acc[m][n] = __builtin_amdgcn_mfma_f32_16x16x32_bf16(
              a[m][0], b[n][1], acc[m][n], 0, 0, 0);
          acc[m][n] = __builtin_amdgcn_mfma_f32_16x16x32_bf16(
              a[m][1], b[n][0], acc[m][n], 0, 0, 0);
          acc[m][n] = __builtin_amdgcn_mfma_f32_16x16x32_bf16(
              a[m][1], b[n][1], acc[m][n], 0, 0, 0);
        }
    }
  }
#undef STAGE

  // gate exchange: D frag (m,n): row = m*16 + (lane>>4)*4 + r, col = n*16 + (lane&15)
  __syncthreads();
#pragma unroll
  for (int m = 0; m < 2; ++m)
#pragma unroll
    for (int n = 0; n < 2; ++n)
#pragma unroll
      for (int r = 0; r < 4; ++r) {
        const int row = m * 16 + (lane >> 4) * 4 + r;
        const int col = n * 16 + (lane & 15);
        z_s[row][g * 32 + col] = acc[m][n][r];
      }
  __syncthreads();

  // epilogue: thread -> 4 (row, hidcol); add P, gates, mask, write h/c/splits
  const int hc = t & 31;
#pragma unroll
  for (int p = 0; p < 4; ++p) {
    const int row  = (t >> 5) * 4 + p;
    const int grow = r0 + row;
    const int token = tok_idx[grow * tok_stride];
    const float* Px = P + (size_t)token * G4;
    const int col = j0 + hc;
    const float zi = z_s[row][hc]      + Px[col];
    const float zf = z_s[row][32 + hc] + Px[HID + col];
    const float zg = z_s[row][64 + hc] + Px[2 * HID + col];
    const float zo = z_s[row][96 + hc] + Px[3 * HID + col];
    const float ig = 1.f / (1.f + expf(-zi));
    const float fg = 1.f / (1.f + expf(-zf));
    const float gg = tanhf(zg);
    const float og = 1.f / (1.f + expf(-zo));
    const float c_old = c[grow * HID + col];
    const float c2 = fg * c_old + ig * gg;
    const float h2 = og * tanhf(c2);
    float hfin;
    if (token != 0) {
      hfin = h2;
      h_out[grow * HID + col] = h2;
      c[grow * HID + col]     = c2;
    } else {
      hfin = h_in[grow * HID + col];
      h_out[grow * HID + col] = hfin;
    }
    // h splits, A-fragment-packed for next step:
    const unsigned short hi = f2bf(hfin);
    const unsigned short lo = f2bf(hfin - bf2f(hi));
    const int kq = hc >> 3, kk = hc & 7;
    const int base =
        ((((ct) * 16 + (grow >> 4)) * 64 + kq * 16 + (grow & 15)) << 3) + kk;
    hpk_out[base] = hi;                       // s=0
    hpk_out[(32 * 16 * 64 << 3) + base] = lo; // s=1 offset = 32*16*64*8
  }
}

// ---------------------------------------------------------------------------
// Decoder output: logits = h @ out_W + out_b; softmax -> y; argmax -> tok.
// ---------------------------------------------------------------------------
__global__ __launch_bounds__(128) void k_logits(
    const float* __restrict__ h, const float* __restrict__ out_W,
    const float* __restrict__ out_b, float* __restrict__ out, int t,
    int* __restrict__ tok) {
  const int b0 = blockIdx.x * 2;
  const int v  = threadIdx.x;

  __shared__ float h_s[2][HID];
  __shared__ float red_v[128];
  __shared__ int   red_i[128];

#pragma unroll
  for (int i = 0; i < 4; ++i) {
    int q  = v + i * 128;
    int r  = q >> 8;
    int kq = (q & 255) * 4;
    *(float4*)&h_s[r][kq] = *(const float4*)&h[(b0 + r) * HID + kq];
  }
  __syncthreads();

  float acc[2];
  acc[0] = out_b[v];
  acc[1] = acc[0];
#pragma unroll 8
  for (int k = 0; k < HID; ++k) {
    const float w = out_W[k * VOC + v];
    acc[0] += h_s[0][k] * w;
    acc[1] += h_s[1][k] * w;
  }

  for (int r = 0; r < 2; ++r) {
    const int b = b0 + r;
    red_v[v] = acc[r];
    red_i[v] = v;
    __syncthreads();
    for (int s = 64; s > 0; s >>= 1) {
      if (v < s) {
        const float ov = red_v[v + s];
        const int   oi = red_i[v + s];
        if (ov > red_v[v] || (ov == red_v[v] && oi < red_i[v])) {
          red_v[v] = ov;
          red_i[v] = oi;
        }
      }
      __syncthreads();
    }
    const float mx  = red_v[0];
    const int amax  = red_i[0];
    __syncthreads();
    const float e = expf(acc[r] - mx);
    red_v[v] = e;
    __syncthreads();
    for (int s = 64; s > 0; s >>= 1) {
      if (v < s) red_v[v] += red_v[v + s];
      __syncthreads();
    }
    const float sum = red_v[0];
    out[b * (LDEC * VOC) + t * VOC + v] = e / sum;
    if (v == 0) {
      tok[b] = amax;
      out[BATCH * LDEC * VOC + t * BATCH + b] = (float)amax;
    }
    __syncthreads();
  }
}

// ---------------------------------------------------------------------------
extern "C" void kernel_launch(void* const* d_in, const int* in_sizes, int n_in,
                              void* d_out, int out_size, void* d_ws,
                              size_t ws_size, hipStream_t stream) {
  (void)in_sizes; (void)n_in; (void)out_size; (void)ws_size;
  const int*   inputs  = (const int*)d_in[0];
  const float* enc_emb = (const float*)d_in[2];
  const float* enc_W   = (const float*)d_in[3];
  const float* enc_U   = (const float*)d_in[4];
  const float* enc_b   = (const float*)d_in[5];
  const float* dec_emb = (const float*)d_in[6];
  const float* dec_W   = (const float*)d_in[7];
  const float* dec_U   = (const float*)d_in[8];
  const float* dec_b   = (const float*)d_in[9];
  const float* out_W   = (const float*)d_in[10];
  const float* out_b   = (const float*)d_in[11];
  float* out = (float*)d_out;

  float* ws    = (float*)d_ws;
  float* P_enc = ws;                        // 512K floats
  float* P_dec = P_enc + VOC * G4;          // 512K
  float* h0    = P_dec + VOC * G4;          // 256K
  float* h1    = h0 + BATCH * HID;          // 256K
  float* c     = h1 + BATCH * HID;          // 256K
  int*   tok   = (int*)(c + BATCH * HID);   // 256 (pad to 256 words)
  unsigned short* enc_hi = (unsigned short*)(tok + 256);  // 4.19M ushort each
  unsigned short* enc_lo = enc_hi + (size_t)HID * G4;
  unsigned short* dec_hi = enc_lo + (size_t)HID * G4;
  unsigned short* dec_lo = dec_hi + (size_t)HID * G4;
  unsigned short* hpk0   = dec_lo + (size_t)HID * G4;     // 512K ushort
  unsigned short* hpk1   = hpk0 + 2 * BATCH * HID;        // 512K ushort

  k_init<<<(BATCH * HID) / 256, 256, 0, stream>>>(h0, c, (unsigned int*)hpk0,
                                                  tok);

  dim3 sgrid((HID * G4) / 256, 2);
  k_split_u<<<sgrid, 256, 0, stream>>>(enc_U, dec_U, enc_hi, enc_lo, dec_hi,
                                       dec_lo);

  dim3 pgrid(G4 / 64, 2, 2);
  k_precompute<<<pgrid, 256, 0, stream>>>(enc_emb, enc_W, enc_b, dec_emb,
                                          dec_W, dec_b, P_enc, P_dec);

  float* hin = h0;  float* hout = h1;
  unsigned short* pin = hpk0;  unsigned short* pout = hpk1;
  for (int t = 0; t < TENC; ++t) {
    k_cell<<<256, 256, 0, stream>>>(hin, hout, c, enc_hi, enc_lo, pin, pout,
                                    P_enc, inputs + t, TENC);
    float* tf = hin; hin = hout; hout = tf;
    unsigned short* tp = pin; pin = pout; pout = tp;
  }
  for (int s = 0; s < LDEC; ++s) {
    k_cell<<<256, 256, 0, stream>>>(hin, hout, c, dec_hi, dec_lo, pin, pout,
                                    P_dec, tok, 1);
    k_logits<<<BATCH / 2, 128, 0, stream>>>(hout, out_W, out_b, out, s, tok);
    float* tf = hin; hin = hout; hout = tf;
    unsigned short* tp = pin; pin = pout; pout = tp;
  }
}

// Round 8
// 3120.634 us; speedup vs baseline: 2.4309x; 1.1825x over previous
//
#include <hip/hip_runtime.h>
#include <hip/hip_bf16.h>

namespace {
constexpr int BATCH = 256;
constexpr int TENC  = 64;
constexpr int HID   = 1024;
constexpr int VOC   = 128;
constexpr int LDEC  = 32;
constexpr int G4    = 4 * HID;  // 4096
}

using short8 = __attribute__((ext_vector_type(8))) short;   // 8 bf16 (4 VGPR)
using f32x4  = __attribute__((ext_vector_type(4))) float;   // MFMA acc

// async global->LDS DMA, 16B per lane (dest = wave-uniform base + lane*16).
__device__ __forceinline__ void async16(const void* g, void* l) {
  __builtin_amdgcn_global_load_lds(
      (const __attribute__((address_space(1))) void*)g,
      (__attribute__((address_space(3))) void*)l, 16, 0, 0);
}

// bf16 round-to-nearest-even split helpers
__device__ __forceinline__ unsigned short f2bf(float x) {
  unsigned int u = __float_as_uint(x);
  return (unsigned short)((u + 0x7fffu + ((u >> 16) & 1u)) >> 16);
}
__device__ __forceinline__ float bf2f(unsigned short h) {
  return __uint_as_float(((unsigned int)h) << 16);
}

// ---------------------------------------------------------------------------
// init: zero h0, c, hpk0; tok = delimiter
// ---------------------------------------------------------------------------
__global__ __launch_bounds__(256) void k_init(float* __restrict__ h0,
                                              float* __restrict__ c,
                                              unsigned int* __restrict__ hpk0,
                                              int* __restrict__ tok) {
  int i = blockIdx.x * 256 + threadIdx.x;  // 0 .. 256*1024-1
  h0[i] = 0.f;
  c[i]  = 0.f;
  hpk0[i] = 0u;  // 2 splits * 256K ushort = 256K dwords
  if (i < BATCH) tok[i] = VOC - 1;
}

// ---------------------------------------------------------------------------
// Split U into bf16 hi/lo, MFMA-B-fragment-packed. OUTPUT-MAJOR traversal:
// thread owns one 16B output chunk (8 consecutive shorts, = one (frag,lane)
// slot); writes are 16B/lane coalesced, reads gather via L2.
// Inverse map (verified == r7 forward map): o = gid*8+kk;
//   w=gid: lanep=w&63 -> kq=lanep>>4, coln=lanep&15; u=w>>6: f=u&7;
//   v2=u>>3: ks=v2&31, ct=v2>>5; k=ks*32+kq*8+kk;
//   n=(f>>1)*1024 + ct*32 + (f&1)*16 + coln.
// grid: (HID*G4/8/256 = 2048, 2)  [y: enc/dec]
// ---------------------------------------------------------------------------
__global__ __launch_bounds__(256) void k_split_u(
    const float* __restrict__ enc_U, const float* __restrict__ dec_U,
    unsigned short* __restrict__ enc_hi, unsigned short* __restrict__ enc_lo,
    unsigned short* __restrict__ dec_hi, unsigned short* __restrict__ dec_lo) {
  const float* U;
  unsigned short *hi_p, *lo_p;
  if (blockIdx.y == 0) { U = enc_U; hi_p = enc_hi; lo_p = enc_lo; }
  else                 { U = dec_U; hi_p = dec_hi; lo_p = dec_lo; }
  const int gid = blockIdx.x * 256 + threadIdx.x;  // chunk index
  const int lanep = gid & 63;
  const int kq = lanep >> 4, coln = lanep & 15;
  const int u = gid >> 6;
  const int f = u & 7;
  const int v2 = u >> 3;
  const int ks = v2 & 31, ct = v2 >> 5;
  const int n = (f >> 1) * HID + ct * 32 + (f & 1) * 16 + coln;
  const int kbase = ks * 32 + kq * 8;

  unsigned short hv[8], lv[8];
#pragma unroll
  for (int kk = 0; kk < 8; ++kk) {
    const float x = U[(size_t)(kbase + kk) * G4 + n];
    hv[kk] = f2bf(x);
    lv[kk] = f2bf(x - bf2f(hv[kk]));
  }
  *(short8*)(hi_p + (size_t)gid * 8) = *(short8*)hv;
  *(short8*)(lo_p + (size_t)gid * 8) = *(short8*)lv;
}

// ---------------------------------------------------------------------------
// Precompute P[v][col] = emb[v] @ W[:,col] + b[col]  (fp32, unchanged r7).
// ---------------------------------------------------------------------------
__global__ __launch_bounds__(256) void k_precompute(
    const float* __restrict__ enc_emb, const float* __restrict__ enc_W,
    const float* __restrict__ enc_b,   const float* __restrict__ dec_emb,
    const float* __restrict__ dec_W,   const float* __restrict__ dec_b,
    float* __restrict__ P_enc, float* __restrict__ P_dec) {
  const float* emb; const float* W; const float* bias; float* P;
  if (blockIdx.z == 0) { emb = enc_emb; W = enc_W; bias = enc_b; P = P_enc; }
  else                 { emb = dec_emb; W = dec_W; bias = dec_b; P = P_dec; }

  __shared__ float A_s[2][64][32];
  __shared__ float B_s[2][32][64];

  const int t    = threadIdx.x;
  const int col0 = blockIdx.x * 64;
  const int v0   = blockIdx.y * 64;
  const int tx   = t & 15;
  const int ty   = t >> 4;
  const int a_row = t >> 3, a_kq = (t & 7) * 4;
  const int b_k   = t >> 4, b_cq = (t & 15) * 4;

  float acc[4][4];
#pragma unroll
  for (int r = 0; r < 4; ++r)
#pragma unroll
    for (int j = 0; j < 4; ++j) acc[r][j] = 0.f;

  async16(&emb[(v0 + a_row) * HID + a_kq], &A_s[0][a_row][a_kq]);
  async16(&emb[(v0 + 32 + a_row) * HID + a_kq], &A_s[0][32 + a_row][a_kq]);
  async16(&W[b_k * G4 + col0 + b_cq], &B_s[0][b_k][b_cq]);
  async16(&W[(16 + b_k) * G4 + col0 + b_cq], &B_s[0][16 + b_k][b_cq]);

  for (int tile = 0; tile < 32; ++tile) {
    const int buf = tile & 1;
    __syncthreads();
    if (tile < 31) {
      const int nb = buf ^ 1;
      const int k0 = (tile + 1) * 32;
      async16(&emb[(v0 + a_row) * HID + k0 + a_kq], &A_s[nb][a_row][a_kq]);
      async16(&emb[(v0 + 32 + a_row) * HID + k0 + a_kq],
              &A_s[nb][32 + a_row][a_kq]);
      async16(&W[(k0 + b_k) * G4 + col0 + b_cq], &B_s[nb][b_k][b_cq]);
      async16(&W[(k0 + 16 + b_k) * G4 + col0 + b_cq],
              &B_s[nb][16 + b_k][b_cq]);
    }
#pragma unroll
    for (int k4 = 0; k4 < 32; k4 += 4) {
      float4 av[4];
#pragma unroll
      for (int r = 0; r < 4; ++r)
        av[r] = *(const float4*)&A_s[buf][ty * 4 + r][k4];
#pragma unroll
      for (int q = 0; q < 4; ++q) {
        const float4 b = *(const float4*)&B_s[buf][k4 + q][tx * 4];
#pragma unroll
        for (int r = 0; r < 4; ++r) {
          const float a = ((const float*)&av[r])[q];
          acc[r][0] += a * b.x;
          acc[r][1] += a * b.y;
          acc[r][2] += a * b.z;
          acc[r][3] += a * b.w;
        }
      }
    }
  }

  const float4 b4 = *(const float4*)&bias[col0 + tx * 4];
#pragma unroll
  for (int r = 0; r < 4; ++r) {
    float4 o;
    o.x = acc[r][0] + b4.x;
    o.y = acc[r][1] + b4.y;
    o.z = acc[r][2] + b4.z;
    o.w = acc[r][3] + b4.w;
    *(float4*)&P[(v0 + ty * 4 + r) * G4 + col0 + tx * 4] = o;
  }
}

// ---------------------------------------------------------------------------
// LSTM step via MFMA, v3: barrier-free K-loop, zero LDS staging.
// Fragments load DIRECTLY global->VGPR (the r7 LDS round-trip was an
// identity copy per lane). 4-deep register pipeline, manual unroll-by-4 so
// phase indices are compile-time (rule #20). Compiler auto-inserts counted
// vmcnt for register deps; waves free-run (no lockstep) until the single
// z_s gate-exchange barrier.
// Block: 32 rows x 128 N (4 gates); wave = gate; per T(=BK32): 8 global
// b128 loads + 16 MFMA. grid: 8 rt x 32 ct = 256 blocks.
// ---------------------------------------------------------------------------
__global__ __launch_bounds__(256, 1) void k_cell(
    const float* __restrict__ h_in, float* __restrict__ h_out,
    float* __restrict__ c,
    const unsigned short* __restrict__ Upk_hi,
    const unsigned short* __restrict__ Upk_lo,
    const unsigned short* __restrict__ hpk_in,
    unsigned short* __restrict__ hpk_out,
    const float* __restrict__ P, const int* __restrict__ tok_idx,
    int tok_stride) {
  const int bx = blockIdx.x;
  const int ct = bx & 31;
  const int rt = bx >> 5;
  const int j0 = ct * 32;
  const int r0 = rt * 32;
  const int t    = threadIdx.x;
  const int lane = t & 63;
  const int g    = t >> 6;  // wave id = gate

  __shared__ float z_s[32][132];

  // fragment pointers at T=0; tile T adds T*ASTR / T*BSTR shorts
  const unsigned short* pa[2][2];  // [m][s]
  const unsigned short* pb[2][2];  // [nf][s]
#pragma unroll
  for (int m = 0; m < 2; ++m)
#pragma unroll
    for (int s = 0; s < 2; ++s)
      pa[m][s] = hpk_in + ((((s * 32) * 16 + (rt * 2 + m)) * 64 + lane) << 3);
#pragma unroll
  for (int nf = 0; nf < 2; ++nf) {
    pb[nf][0] = Upk_hi + (((ct * 32 * 8 + (g * 2 + nf)) * 64 + lane) << 3);
    pb[nf][1] = Upk_lo + (((ct * 32 * 8 + (g * 2 + nf)) * 64 + lane) << 3);
  }
  constexpr int ASTR = 16 * 64 * 8;  // 8192 shorts per k-tile
  constexpr int BSTR = 8 * 64 * 8;   // 4096 shorts per k-tile

  short8 a[4][2][2], b[4][2][2];  // [phase][m|nf][s]
  f32x4 acc[2][2];
#pragma unroll
  for (int m = 0; m < 2; ++m)
#pragma unroll
    for (int n = 0; n < 2; ++n) acc[m][n] = (f32x4){0.f, 0.f, 0.f, 0.f};

#define LOADT(T, p)                                                          \
  {                                                                          \
    _Pragma("unroll") for (int m = 0; m < 2; ++m)                            \
        _Pragma("unroll") for (int s = 0; s < 2; ++s)                        \
            a[p][m][s] = *(const short8*)(pa[m][s] + (T) * ASTR);            \
    _Pragma("unroll") for (int nf = 0; nf < 2; ++nf)                         \
        _Pragma("unroll") for (int s = 0; s < 2; ++s)                        \
            b[p][nf][s] = *(const short8*)(pb[nf][s] + (T) * BSTR);          \
  }
#define MFMAT(p)                                                             \
  _Pragma("unroll") for (int m = 0; m < 2; ++m)                              \
      _Pragma("unroll") for (int n = 0; n < 2; ++n) {                        \
    acc[m][n] = __builtin_amdgcn_mfma_f32_16x16x32_bf16(                     \
        a[p][m][0], b[p][n][0], acc[m][n], 0, 0, 0);                         \
    acc[m][n] = __builtin_amdgcn_mfma_f32_16x16x32_bf16(                     \
        a[p][m][0], b[p][n][1], acc[m][n], 0, 0, 0);                         \
    acc[m][n] = __builtin_amdgcn_mfma_f32_16x16x32_bf16(                     \
        a[p][m][1], b[p][n][0], acc[m][n], 0, 0, 0);                         \
    acc[m][n] = __builtin_amdgcn_mfma_f32_16x16x32_bf16(                     \
        a[p][m][1], b[p][n][1], acc[m][n], 0, 0, 0);                         \
  }

  LOADT(0, 0)
  LOADT(1, 1)
  LOADT(2, 2)
  LOADT(3, 3)

  for (int T = 0; T < 32; T += 4) {
    MFMAT(0)
    if (T + 4 < 32) LOADT(T + 4, 0)
    MFMAT(1)
    if (T + 5 < 32) LOADT(T + 5, 1)
    MFMAT(2)
    if (T + 6 < 32) LOADT(T + 6, 2)
    MFMAT(3)
    if (T + 7 < 32) LOADT(T + 7, 3)
  }
#undef LOADT
#undef MFMAT

  // gate exchange: D frag (m,n): row = m*16+(lane>>4)*4+r, col = n*16+(lane&15)
#pragma unroll
  for (int m = 0; m < 2; ++m)
#pragma unroll
    for (int n = 0; n < 2; ++n)
#pragma unroll
      for (int r = 0; r < 4; ++r) {
        const int row = m * 16 + (lane >> 4) * 4 + r;
        const int col = n * 16 + (lane & 15);
        z_s[row][g * 32 + col] = acc[m][n][r];
      }
  __syncthreads();

  // epilogue: thread -> 4 (row, hidcol); add P, gates, mask, write h/c/splits
  const int hc = t & 31;
#pragma unroll
  for (int p = 0; p < 4; ++p) {
    const int row  = (t >> 5) * 4 + p;
    const int grow = r0 + row;
    const int token = tok_idx[grow * tok_stride];
    const float* Px = P + (size_t)token * G4;
    const int col = j0 + hc;
    const float zi = z_s[row][hc]      + Px[col];
    const float zf = z_s[row][32 + hc] + Px[HID + col];
    const float zg = z_s[row][64 + hc] + Px[2 * HID + col];
    const float zo = z_s[row][96 + hc] + Px[3 * HID + col];
    const float ig = 1.f / (1.f + expf(-zi));
    const float fg = 1.f / (1.f + expf(-zf));
    const float gg = tanhf(zg);
    const float og = 1.f / (1.f + expf(-zo));
    const float c_old = c[grow * HID + col];
    const float c2 = fg * c_old + ig * gg;
    const float h2 = og * tanhf(c2);
    float hfin;
    if (token != 0) {
      hfin = h2;
      h_out[grow * HID + col] = h2;
      c[grow * HID + col]     = c2;
    } else {
      hfin = h_in[grow * HID + col];
      h_out[grow * HID + col] = hfin;
    }
    // h splits, A-fragment-packed for next step:
    const unsigned short hi = f2bf(hfin);
    const unsigned short lo = f2bf(hfin - bf2f(hi));
    const int kq = hc >> 3, kk = hc & 7;
    const int base =
        ((((ct) * 16 + (grow >> 4)) * 64 + kq * 16 + (grow & 15)) << 3) + kk;
    hpk_out[base] = hi;                       // s=0
    hpk_out[(32 * 16 * 64 << 3) + base] = lo; // s=1 offset = 32*16*64*8
  }
}

// ---------------------------------------------------------------------------
// Decoder output: logits = h @ out_W + out_b; softmax -> y; argmax -> tok.
// ---------------------------------------------------------------------------
__global__ __launch_bounds__(128) void k_logits(
    const float* __restrict__ h, const float* __restrict__ out_W,
    const float* __restrict__ out_b, float* __restrict__ out, int t,
    int* __restrict__ tok) {
  const int b0 = blockIdx.x * 2;
  const int v  = threadIdx.x;

  __shared__ float h_s[2][HID];
  __shared__ float red_v[128];
  __shared__ int   red_i[128];

#pragma unroll
  for (int i = 0; i < 4; ++i) {
    int q  = v + i * 128;
    int r  = q >> 8;
    int kq = (q & 255) * 4;
    *(float4*)&h_s[r][kq] = *(const float4*)&h[(b0 + r) * HID + kq];
  }
  __syncthreads();

  float acc[2];
  acc[0] = out_b[v];
  acc[1] = acc[0];
#pragma unroll 8
  for (int k = 0; k < HID; ++k) {
    const float w = out_W[k * VOC + v];
    acc[0] += h_s[0][k] * w;
    acc[1] += h_s[1][k] * w;
  }

  for (int r = 0; r < 2; ++r) {
    const int b = b0 + r;
    red_v[v] = acc[r];
    red_i[v] = v;
    __syncthreads();
    for (int s = 64; s > 0; s >>= 1) {
      if (v < s) {
        const float ov = red_v[v + s];
        const int   oi = red_i[v + s];
        if (ov > red_v[v] || (ov == red_v[v] && oi < red_i[v])) {
          red_v[v] = ov;
          red_i[v] = oi;
        }
      }
      __syncthreads();
    }
    const float mx  = red_v[0];
    const int amax  = red_i[0];
    __syncthreads();
    const float e = expf(acc[r] - mx);
    red_v[v] = e;
    __syncthreads();
    for (int s = 64; s > 0; s >>= 1) {
      if (v < s) red_v[v] += red_v[v + s];
      __syncthreads();
    }
    const float sum = red_v[0];
    out[b * (LDEC * VOC) + t * VOC + v] = e / sum;
    if (v == 0) {
      tok[b] = amax;
      out[BATCH * LDEC * VOC + t * BATCH + b] = (float)amax;
    }
    __syncthreads();
  }
}

// ---------------------------------------------------------------------------
extern "C" void kernel_launch(void* const* d_in, const int* in_sizes, int n_in,
                              void* d_out, int out_size, void* d_ws,
                              size_t ws_size, hipStream_t stream) {
  (void)in_sizes; (void)n_in; (void)out_size; (void)ws_size;
  const int*   inputs  = (const int*)d_in[0];
  const float* enc_emb = (const float*)d_in[2];
  const float* enc_W   = (const float*)d_in[3];
  const float* enc_U   = (const float*)d_in[4];
  const float* enc_b   = (const float*)d_in[5];
  const float* dec_emb = (const float*)d_in[6];
  const float* dec_W   = (const float*)d_in[7];
  const float* dec_U   = (const float*)d_in[8];
  const float* dec_b   = (const float*)d_in[9];
  const float* out_W   = (const float*)d_in[10];
  const float* out_b   = (const float*)d_in[11];
  float* out = (float*)d_out;

  float* ws    = (float*)d_ws;
  float* P_enc = ws;                        // 512K floats
  float* P_dec = P_enc + VOC * G4;          // 512K
  float* h0    = P_dec + VOC * G4;          // 256K
  float* h1    = h0 + BATCH * HID;          // 256K
  float* c     = h1 + BATCH * HID;          // 256K
  int*   tok   = (int*)(c + BATCH * HID);   // 256 (pad to 256 words)
  unsigned short* enc_hi = (unsigned short*)(tok + 256);  // 4.19M ushort each
  unsigned short* enc_lo = enc_hi + (size_t)HID * G4;
  unsigned short* dec_hi = enc_lo + (size_t)HID * G4;
  unsigned short* dec_lo = dec_hi + (size_t)HID * G4;
  unsigned short* hpk0   = dec_lo + (size_t)HID * G4;     // 512K ushort
  unsigned short* hpk1   = hpk0 + 2 * BATCH * HID;        // 512K ushort

  k_init<<<(BATCH * HID) / 256, 256, 0, stream>>>(h0, c, (unsigned int*)hpk0,
                                                  tok);

  dim3 sgrid((HID * G4) / 8 / 256, 2);
  k_split_u<<<sgrid, 256, 0, stream>>>(enc_U, dec_U, enc_hi, enc_lo, dec_hi,
                                       dec_lo);

  dim3 pgrid(G4 / 64, 2, 2);
  k_precompute<<<pgrid, 256, 0, stream>>>(enc_emb, enc_W, enc_b, dec_emb,
                                          dec_W, dec_b, P_enc, P_dec);

  float* hin = h0;  float* hout = h1;
  unsigned short* pin = hpk0;  unsigned short* pout = hpk1;
  for (int t = 0; t < TENC; ++t) {
    k_cell<<<256, 256, 0, stream>>>(hin, hout, c, enc_hi, enc_lo, pin, pout,
                                    P_enc, inputs + t, TENC);
    float* tf = hin; hin = hout; hout = tf;
    unsigned short* tp = pin; pin = pout; pout = tp;
  }
  for (int s = 0; s < LDEC; ++s) {
    k_cell<<<256, 256, 0, stream>>>(hin, hout, c, dec_hi, dec_lo, pin, pout,
                                    P_dec, tok, 1);
    k_logits<<<BATCH / 2, 128, 0, stream>>>(hout, out_W, out_b, out, s, tok);
    float* tf = hin; hin = hout; hout = tf;
    unsigned short* tp = pin; pin = pout; pout = tp;
  }
}